// Round 2
// baseline (867.956 us; speedup 1.0000x reference)
//
#include <hip/hip_runtime.h>

#define VOCAB 50257
#define NB 512
#define NT 2048
#define NOUT 128

// sigmoid via exp2/rcp: sig(x) = 1/(1+2^(-x*log2e))
__device__ __forceinline__ float sigf(float x){
    return __builtin_amdgcn_rcpf(1.0f + __builtin_amdgcn_exp2f(-1.4426950408889634f*x));
}
// tanh(x) = 1 - 2/(1+e^(2x)) = 1 - 2*rcp(1+2^(x*2*log2e))
__device__ __forceinline__ float tanhfast(float x){
    return fmaf(-2.0f, __builtin_amdgcn_rcpf(1.0f + __builtin_amdgcn_exp2f(2.8853900817779268f*x)), 1.0f);
}

// K1: tab[v][k][g] = b0[2g+k] + sum_d emb[v][d] * Wih0[2g+k][d]
// layout chosen so lane k of a row pair does one float4 load for its 4 gates.
__global__ __launch_bounds__(256) void build_table(const float* __restrict__ emb,
                                                   const float* __restrict__ Wih0,
                                                   const float* __restrict__ b0,
                                                   float* __restrict__ tab){
    int v = blockIdx.x*256 + threadIdx.x;
    if (v >= VOCAB) return;
    const float4* ep = (const float4*)(emb + v*8);
    float4 e0 = ep[0], e1 = ep[1];
    float e[8] = {e0.x,e0.y,e0.z,e0.w,e1.x,e1.y,e1.z,e1.w};
    float o[8];
#pragma unroll
    for (int j=0;j<8;j++){
        float s = b0[j];
#pragma unroll
        for (int d=0;d<8;d++) s = fmaf(e[d], Wih0[j*8+d], s);
        o[j]=s;
    }
    float4* tp = (float4*)(tab + v*8);
    tp[0] = make_float4(o[0],o[2],o[4],o[6]);  // k=0: j=0,2,4,6 (i,f,g,o elem 0)
    tp[1] = make_float4(o[1],o[3],o[5],o[7]);  // k=1
}

// K2: sequential scan. 2 lanes per batch row: lane k owns h[k],c[k] of both layers.
// 16 blocks x 64 threads = 32 rows/block.
__global__ __launch_bounds__(64) void lstm_scan(const int* __restrict__ x,
                                                const float* __restrict__ tab,
                                                const float* __restrict__ Whh0,
                                                const float* __restrict__ Wih1,
                                                const float* __restrict__ Whh1,
                                                const float* __restrict__ b1,
                                                float* __restrict__ y1out,   // [T][B][2]
                                                float* __restrict__ tail){   // h_n,c_n at d_out+B*T*128
    const int tid = threadIdx.x;
    const int k = tid & 1;
    const int row = blockIdx.x*32 + (tid>>1);
    // per-lane weight copies; _ow multiplies own element, _ot the shuffled one
    float w00[4],w01[4],wi0[4],wi1[4],wh0[4],wh1[4],bg[4];
#pragma unroll
    for (int g=0; g<4; g++){
        int j = 2*g+k;               // gate order from split: i,f,g,o ; element k
        w00[g]=Whh0[j*2+k];  w01[g]=Whh0[j*2+(k^1)];
        wi0[g]=Wih1[j*2+k];  wi1[g]=Wih1[j*2+(k^1)];
        wh0[g]=Whh1[j*2+k];  wh1[g]=Whh1[j*2+(k^1)];
        bg[g]=b1[j];
    }
    const int* __restrict__ xr = x + row*NT;
    const float4* __restrict__ tab4 = (const float4*)tab;
    float h0=0.f,c0=0.f,h1=0.f,c1=0.f;
    int idx1 = xr[0];
    float4 gx = tab4[idx1*2+k];      // gates_x for t=0 (includes b0)
    idx1 = xr[1];
    for (int t=0;t<NT;t++){
        const int   idx2 = (t+2<NT) ? xr[t+2] : 0;   // token prefetch, 2 deep
        const float4 gxn = tab4[idx1*2+k];           // table prefetch, 1 deep
        // ---- layer 0 ----
        float ho = __shfl_xor(h0,1);
        float ai = fmaf(w00[0],h0, fmaf(w01[0],ho, gx.x));
        float af = fmaf(w00[1],h0, fmaf(w01[1],ho, gx.y));
        float ag = fmaf(w00[2],h0, fmaf(w01[2],ho, gx.z));
        float ao = fmaf(w00[3],h0, fmaf(w01[3],ho, gx.w));
        float si=sigf(ai), sf=sigf(af), tg=tanhfast(ag), so=sigf(ao);
        c0 = fmaf(sf,c0, si*tg);
        h0 = so*tanhfast(c0);
        // ---- layer 1 ----
        float h0o = __shfl_xor(h0,1);
        float h1o = __shfl_xor(h1,1);
        float bi_ = fmaf(wi0[0],h0, fmaf(wi1[0],h0o, fmaf(wh0[0],h1, fmaf(wh1[0],h1o, bg[0]))));
        float bf_ = fmaf(wi0[1],h0, fmaf(wi1[1],h0o, fmaf(wh0[1],h1, fmaf(wh1[1],h1o, bg[1]))));
        float bgg = fmaf(wi0[2],h0, fmaf(wi1[2],h0o, fmaf(wh0[2],h1, fmaf(wh1[2],h1o, bg[2]))));
        float bo_ = fmaf(wi0[3],h0, fmaf(wi1[3],h0o, fmaf(wh0[3],h1, fmaf(wh1[3],h1o, bg[3]))));
        float si1=sigf(bi_), sf1=sigf(bf_), tg1=tanhfast(bgg), so1=sigf(bo_);
        c1 = fmaf(sf1,c1, si1*tg1);
        h1 = so1*tanhfast(c1);
        // coalesced: 32 rows of a wave write 256B contiguous at step t
        y1out[(t*NB + row)*2 + k] = h1;
        gx = gxn; idx1 = idx2;
    }
    // h_n: [2][B][2], then c_n: [2][B][2]
    tail[row*2+k]            = h0;
    tail[NB*2 + row*2+k]     = h1;
    tail[2*NB*2 + row*2+k]   = c0;
    tail[3*NB*2 + row*2+k]   = c1;
}

// K3: out[bt][j] = y1[bt]·Wfc[j][:] + bfc[j]; one float4 store per thread.
__global__ __launch_bounds__(256) void fc_out(const float* __restrict__ y1,
                                              const float* __restrict__ Wfc,
                                              const float* __restrict__ bfc,
                                              float* __restrict__ out){
    const int tid = threadIdx.x;
    const int j4  = tid & 31;        // 32 threads cover 128 outputs (x4)
    const int btl = tid >> 5;        // 8 (b,t) pairs per block
    const int bt  = blockIdx.x*8 + btl;
    const int b   = bt >> 11;        // /T
    const int tt  = bt & (NT-1);
    const float2 y  = *(const float2*)(y1 + (tt*NB + b)*2);
    const float4 wa = *(const float4*)(Wfc + j4*8);
    const float4 wb = *(const float4*)(Wfc + j4*8+4);
    const float4 bb = *(const float4*)(bfc + j4*4);
    float4 o;
    o.x = fmaf(y.x,wa.x, fmaf(y.y,wa.y, bb.x));
    o.y = fmaf(y.x,wa.z, fmaf(y.y,wa.w, bb.y));
    o.z = fmaf(y.x,wb.x, fmaf(y.y,wb.y, bb.z));
    o.w = fmaf(y.x,wb.z, fmaf(y.y,wb.w, bb.w));
    *(float4*)(out + bt*128 + j4*4) = o;
}

extern "C" void kernel_launch(void* const* d_in, const int* in_sizes, int n_in,
                              void* d_out, int out_size, void* d_ws, size_t ws_size,
                              hipStream_t stream){
    const int*   x    = (const int*)d_in[0];
    const float* emb  = (const float*)d_in[1];
    const float* Wih0 = (const float*)d_in[2];
    const float* Whh0 = (const float*)d_in[3];
    const float* b0   = (const float*)d_in[4];
    const float* Wih1 = (const float*)d_in[5];
    const float* Whh1 = (const float*)d_in[6];
    const float* b1   = (const float*)d_in[7];
    const float* Wfc  = (const float*)d_in[8];
    const float* bfc  = (const float*)d_in[9];
    float* out  = (float*)d_out;
    float* tab  = (float*)d_ws;                       // VOCAB*8 floats = 1.6 MB
    float* y1   = tab + (size_t)VOCAB*8;              // T*B*2 floats = 8 MB
    float* tail = out + (size_t)NB*NT*NOUT;           // h_n|c_n region of d_out

    build_table<<<(VOCAB+255)/256, 256, 0, stream>>>(emb, Wih0, b0, tab);
    lstm_scan<<<NB/32, 64, 0, stream>>>(x, tab, Whh0, Wih1, Whh1, b1, y1, tail);
    fc_out<<<(NB*NT)/8, 256, 0, stream>>>(y1, Wfc, bfc, out);
}